// Round 1
// baseline (238.305 us; speedup 1.0000x reference)
//
#include <hip/hip_runtime.h>
#include <math.h>

#define SDIM 3
#define BDIM 32
#define NPRI 2000
#define LDIM 4
#define DDIM 78
#define NOFF 72
#define NSB (SDIM * BDIM)   // 96

// ---------------------------------------------------------------------------
// Kernel 1: per-(s,b) cost matrix in LDS + greedy assignment (jnp.argmin
// semantics: first occurrence wins on ties; used rows masked to +inf).
// grid: (96, 2)  block: 256
// ---------------------------------------------------------------------------
__global__ __launch_bounds__(256) void assign_kernel(
    const float* __restrict__ predsA, const float* __restrict__ predsB,
    const float* __restrict__ gt, int* __restrict__ rowsA, int* __restrict__ rowsB)
{
    const int sb = blockIdx.x;          // s*B + b
    const int branch = blockIdx.y;
    const float* preds = branch ? predsB : predsA;
    int* rows = branch ? rowsB : rowsA;
    const int b = sb % BDIM;
    const int tid = threadIdx.x;

    __shared__ float tg_geo[LDIM][4];
    __shared__ float tg_off[LDIM][NOFF];
    __shared__ float cost[NPRI * 5];    // stride 5 to break bank conflicts
    __shared__ float red_val[256];
    __shared__ int   red_idx[256];

    // stage gt[b] (pre-divide offsets by IMG_W-1 = 799, as the reference does)
    for (int i = tid; i < LDIM * DDIM; i += 256) {
        int l = i / DDIM, j = i % DDIM;
        float v = gt[((size_t)b * LDIM + l) * DDIM + j];
        if (j >= 6)      tg_off[l][j - 6] = v / 799.0f;
        else if (j >= 2) tg_geo[l][j - 2] = v;
    }
    __syncthreads();

    const float* pbase = preds + (size_t)sb * NPRI * DDIM;
    for (int n = tid; n < NPRI; n += 256) {
        const float* p = pbase + (size_t)n * DDIM;
        float a = p[0], b1 = p[1];
        float m = fmaxf(a, b1);
        float ea = expf(a - m), eb = expf(b1 - m);
        float score = eb / (ea + eb);
        float g0 = p[2], g1 = p[3], g2 = p[4], g3 = p[5];
        float geo[LDIM], offs[LDIM];
#pragma unroll
        for (int l = 0; l < LDIM; ++l) {
            geo[l] = fabsf(g0 - tg_geo[l][0]) + fabsf(g1 - tg_geo[l][1])
                   + fabsf(g2 - tg_geo[l][2]) + fabsf(g3 - tg_geo[l][3]);
            offs[l] = 0.0f;
        }
        for (int j = 0; j < NOFF; ++j) {
            float pv = p[6 + j];
#pragma unroll
            for (int l = 0; l < LDIM; ++l) offs[l] += fabsf(pv - tg_off[l][j]);
        }
#pragma unroll
        for (int l = 0; l < LDIM; ++l)
            cost[n * 5 + l] = geo[l] + offs[l] / 72.0f - score;
    }
    __syncthreads();

    // greedy: for each target column l in order, global argmin over priors
    for (int l = 0; l < LDIM; ++l) {
        float bv = INFINITY; int bi = 0x7fffffff;
        for (int n = tid; n < NPRI; n += 256) {
            float v = cost[n * 5 + l];
            if (v < bv) { bv = v; bi = n; }   // strict < keeps first occurrence
        }
        red_val[tid] = bv; red_idx[tid] = bi;
        __syncthreads();
        for (int s = 128; s > 0; s >>= 1) {
            if (tid < s) {
                float v2 = red_val[tid + s]; int i2 = red_idx[tid + s];
                if (v2 < red_val[tid] || (v2 == red_val[tid] && i2 < red_idx[tid])) {
                    red_val[tid] = v2; red_idx[tid] = i2;
                }
            }
            __syncthreads();
        }
        int r = red_idx[0];
        if (tid == 0) {
            rows[sb * LDIM + l] = r;
            cost[r * 5 + 0] = INFINITY; cost[r * 5 + 1] = INFINITY;
            cost[r * 5 + 2] = INFINITY; cost[r * 5 + 3] = INFINITY;
        }
        __syncthreads();
    }
}

// ---------------------------------------------------------------------------
// Kernel 2: focal cls loss per prior, summed over (s,b), /96.
// grid: (8, 2)  block: 256
// ---------------------------------------------------------------------------
__global__ __launch_bounds__(256) void cls_kernel(
    const float* __restrict__ predsA, const float* __restrict__ predsB,
    const int* __restrict__ rowsA, const int* __restrict__ rowsB,
    float* __restrict__ clsA, float* __restrict__ clsB)
{
    const int branch = blockIdx.y;
    const float* preds = branch ? predsB : predsA;
    const int* rows = branch ? rowsB : rowsA;
    float* cls = branch ? clsB : clsA;

    __shared__ int r[NSB * LDIM];
    const int tid = threadIdx.x;
    for (int i = tid; i < NSB * LDIM; i += 256) r[i] = rows[i];
    __syncthreads();

    int n = blockIdx.x * 256 + tid;
    if (n >= NPRI) return;

    float acc = 0.0f;
    for (int sb = 0; sb < NSB; ++sb) {
        const float* p = preds + ((size_t)sb * NPRI + n) * DDIM;
        float a = p[0], b1 = p[1];
        const int* rr = &r[sb * LDIM];
        bool matched = (rr[0] == n) || (rr[1] == n) || (rr[2] == n) || (rr[3] == n);
        float m = fmaxf(a, b1);
        float lse = m + logf(expf(a - m) + expf(b1 - m));
        float logpt = (matched ? b1 : a) - lse;
        float pt = expf(logpt);
        float alpha = matched ? 0.9f : 0.1f;
        float om = 1.0f - pt;
        acc += -(alpha * om * om * logpt);
    }
    cls[n] = acc / 96.0f;
}

// ---------------------------------------------------------------------------
// Kernel 3: reg (smooth-L1) + line-IoU on matched priors, reduced to [L].
// grid: 2 blocks (one per branch), block: 384 (= 96 sb * 4 l)
// out layout: out[0..3] = reg_loss[l], out[4..7] = iou_loss[l]
// ---------------------------------------------------------------------------
__global__ __launch_bounds__(384) void regiou_kernel(
    const float* __restrict__ predsA, const float* __restrict__ predsB,
    const float* __restrict__ gt,
    const int* __restrict__ rowsA, const int* __restrict__ rowsB,
    float* __restrict__ regiouA, float* __restrict__ regiouB)
{
    const int branch = blockIdx.x;
    const float* preds = branch ? predsB : predsA;
    const int* rows = branch ? rowsB : rowsA;
    float* out = branch ? regiouB : regiouA;

    __shared__ float regbuf[NSB * LDIM];
    __shared__ float ioubuf[NSB * LDIM];

    const int t = threadIdx.x;          // 0..383
    const int l = t & 3, sb = t >> 2;
    const int b = sb % BDIM;
    const int rr = rows[sb * LDIM + l];
    const float* pm = preds + ((size_t)sb * NPRI + rr) * DDIM;
    const float* tg = gt + ((size_t)b * LDIM + l) * DDIM;

    const float scv[4] = {71.0f, 799.0f, 180.0f, 71.0f};
    float rsum = 0.0f;
#pragma unroll
    for (int j = 0; j < 4; ++j) {
        float d = pm[2 + j] * scv[j] - tg[2 + j] * scv[j];
        float ad = fabsf(d);
        rsum += (ad < 1.0f) ? 0.5f * d * d : ad - 0.5f;
    }
    regbuf[t] = (rsum / 4.0f) / 4.0f;   // mean over 4 dims, then /L

    float osum = 0.0f, usum = 0.0f;
    for (int j = 0; j < NOFF; ++j) {
        float rp = pm[6 + j] * 799.0f;
        float rt = tg[6 + j];
        float ov = fminf(rp + 15.0f, rt + 15.0f) - fmaxf(rp - 15.0f, rt - 15.0f);
        float un = fmaxf(rp + 15.0f, rt + 15.0f) - fminf(rp - 15.0f, rt - 15.0f);
        bool inv = (rt < 0.0f) || (rt >= 800.0f);
        if (inv) { ov = 0.0f; un = 0.0f; }
        osum += ov; usum += un;
    }
    float iou = osum / (usum + 1e-9f);
    ioubuf[t] = (1.0f - iou) / 4.0f;    // /L
    __syncthreads();

    if (t < 8) {
        int l2 = t & 3; bool isiou = t >= 4;
        const float* buf = isiou ? ioubuf : regbuf;
        float s = 0.0f;
        for (int sb2 = 0; sb2 < NSB; ++sb2) s += buf[sb2 * LDIM + l2];
        out[t] = s / 96.0f;
    }
}

// ---------------------------------------------------------------------------
// Kernel 4: inst_A/inst_B, exact even-N median via bitonic sort (2048, +inf
// padded), weighted sum -> scalar.
// grid: 1 block, 1024 threads
// ---------------------------------------------------------------------------
__global__ __launch_bounds__(1024) void final_kernel(
    const float* __restrict__ clsA, const float* __restrict__ clsB,
    const float* __restrict__ regiouA, const float* __restrict__ regiouB,
    const int* __restrict__ rowsA, const int* __restrict__ rowsB,
    const float* __restrict__ diff, float* __restrict__ out)
{
    __shared__ float instA[NPRI];
    __shared__ float instB[NPRI];
    __shared__ float sbuf[2048];
    __shared__ float red[1024];
    const int tid = threadIdx.x;

    for (int n = tid; n < NPRI; n += 1024) {
        float ia = clsA[n] * 2.0f;
        float ib = clsB[n] * 2.0f;
#pragma unroll
        for (int l = 0; l < 4; ++l) {
            if (rowsA[(NSB - 1) * LDIM + l] == n)
                ia += regiouA[l] * 0.5f + regiouA[4 + l] * 2.0f;
            if (rowsB[(NSB - 1) * LDIM + l] == n)
                ib += regiouB[l] * 0.5f + regiouB[4 + l] * 2.0f;
        }
        instA[n] = ia; instB[n] = ib;
        sbuf[n] = ia - ib;
    }
    if (tid < 2048 - NPRI) sbuf[NPRI + tid] = INFINITY;
    __syncthreads();

    // bitonic sort ascending, 2048 elements, 1024 threads
    for (int k = 2; k <= 2048; k <<= 1) {
        for (int j = k >> 1; j > 0; j >>= 1) {
            for (int i = tid; i < 2048; i += 1024) {
                int ixj = i ^ j;
                if (ixj > i) {
                    bool up = ((i & k) == 0);
                    float x = sbuf[i], y = sbuf[ixj];
                    if ((x > y) == up) { sbuf[i] = y; sbuf[ixj] = x; }
                }
            }
            __syncthreads();
        }
    }

    float delta = 0.5f * (sbuf[999] + sbuf[1000]);   // median of 2000 values

    float acc = 0.0f;
    for (int n = tid; n < NPRI; n += 1024) {
        float dm = (diff[n] + diff[NPRI + n] + diff[2 * NPRI + n]) / 3.0f;
        acc += (1.0f - dm) * (instA[n] - 0.5f * delta)
             + dm * (instB[n] + 0.5f * delta);
    }
    red[tid] = acc;
    __syncthreads();
    for (int s = 512; s > 0; s >>= 1) {
        if (tid < s) red[tid] += red[tid + s];
        __syncthreads();
    }
    if (tid == 0) out[0] = red[0];
}

// ---------------------------------------------------------------------------
extern "C" void kernel_launch(void* const* d_in, const int* in_sizes, int n_in,
                              void* d_out, int out_size, void* d_ws, size_t ws_size,
                              hipStream_t stream)
{
    const float* predsA = (const float*)d_in[0];   // [3,32,2000,78]
    const float* predsB = (const float*)d_in[1];   // [3,32,2000,78]
    const float* gt     = (const float*)d_in[2];   // [32,4,78]
    const float* diff   = (const float*)d_in[3];   // [3,2000]
    float* out = (float*)d_out;

    // workspace layout (all fully written before read; no zero-init needed)
    int* rowsA = (int*)d_ws;                 // 384 ints
    int* rowsB = rowsA + NSB * LDIM;         // 384 ints
    float* clsA = (float*)(rowsB + NSB * LDIM);  // 2000 f
    float* clsB = clsA + NPRI;                   // 2000 f
    float* regiouA = clsB + NPRI;                // 8 f
    float* regiouB = regiouA + 8;                // 8 f

    dim3 g1(NSB, 2);
    assign_kernel<<<g1, 256, 0, stream>>>(predsA, predsB, gt, rowsA, rowsB);

    dim3 g2((NPRI + 255) / 256, 2);
    cls_kernel<<<g2, 256, 0, stream>>>(predsA, predsB, rowsA, rowsB, clsA, clsB);

    regiou_kernel<<<2, 384, 0, stream>>>(predsA, predsB, gt, rowsA, rowsB,
                                         regiouA, regiouB);

    final_kernel<<<1, 1024, 0, stream>>>(clsA, clsB, regiouA, regiouB,
                                         rowsA, rowsB, diff, out);
}

// Round 2
// 215.906 us; speedup vs baseline: 1.1037x; 1.1037x over previous
//
#include <hip/hip_runtime.h>
#include <math.h>

#define SDIM 3
#define BDIM 32
#define NPRI 2000
#define LDIM 4
#define DDIM 78
#define NOFF 72
#define NSB (SDIM * BDIM)   // 96
#define CHUNK 128
#define NCHUNK 16           // ceil(2000/128)

// ---------------------------------------------------------------------------
// ws layout (floats unless noted):
//   costws  [2][96][4][2000]   6,144,000 B
//   negws   [2][96][2000]      1,536,000 B
//   rowsws  [2][96][4] (int)       3,072 B
//   clsSum  [2][2000]             16,000 B
//   regiou  [2][8]                    64 B
// total ~7.7 MB
// ---------------------------------------------------------------------------

// Kernel 1: coalesced cost matrix + all-negative focal term.
// grid: (16 chunks, 96 sb, 2 branches), block 256 (2 threads per prior)
__global__ __launch_bounds__(256) void cost_kernel(
    const float* __restrict__ predsA, const float* __restrict__ predsB,
    const float* __restrict__ gt, float* __restrict__ costws,
    float* __restrict__ negws)
{
    const int chunk = blockIdx.x;
    const int sb = blockIdx.y;
    const int branch = blockIdx.z;
    const float* preds = branch ? predsB : predsA;
    const int bimg = sb % BDIM;
    const int tid = threadIdx.x;
    const int base_n = chunk * CHUNK;
    const int ntile = min(CHUNK, NPRI - base_n);

    __shared__ float tile[CHUNK * DDIM];       // 39,936 B
    __shared__ float tg_geo[LDIM][4];
    __shared__ float tg_off[LDIM][NOFF];
    __shared__ float part[CHUNK][5];           // pad 5 to spread banks

    // stage gt[bimg] (pre-divide offsets by 799 as reference does)
    for (int i = tid; i < LDIM * DDIM; i += 256) {
        int l = i / DDIM, j = i % DDIM;
        float v = gt[((size_t)bimg * LDIM + l) * DDIM + j];
        if (j >= 6)      tg_off[l][j - 6] = v / 799.0f;
        else if (j >= 2) tg_geo[l][j - 2] = v;
    }
    // stage prior tile, fully coalesced float4 (offset is 16B-aligned: see note)
    // (sb*2000 + chunk*128) = 8*(250*sb + 16*chunk) -> *78 floats divisible by 4
    {
        const float4* src = (const float4*)(preds + ((size_t)sb * NPRI + base_n) * DDIM);
        float4* dst = (float4*)tile;
        const int nf4 = ntile * DDIM / 4;      // 2496 or 1560, both exact
        for (int k = tid; k < nf4; k += 256) dst[k] = src[k];
    }
    __syncthreads();

    const int i = tid >> 1, h = tid & 1;
    const int n = base_n + i;
    float offs[LDIM] = {0.f, 0.f, 0.f, 0.f};

    if (i < ntile) {
        const float* p = &tile[i * DDIM];
        const int j0 = h * 36;
        for (int j = j0; j < j0 + 36; ++j) {
            float pv = p[6 + j];
#pragma unroll
            for (int l = 0; l < LDIM; ++l) offs[l] += fabsf(pv - tg_off[l][j]);
        }
        if (h == 1) {
#pragma unroll
            for (int l = 0; l < LDIM; ++l) part[i][l] = offs[l];
            // all-negative focal term for this (sb, n)
            float a = p[0], b1 = p[1];
            float m = fmaxf(a, b1);
            float ea = expf(a - m), eb = expf(b1 - m);
            float lse = m + logf(ea + eb);
            float logpt = a - lse;
            float pt = expf(logpt);
            float om = 1.0f - pt;
            negws[(size_t)(branch * NSB + sb) * NPRI + n] = -(0.1f * om * om * logpt);
        }
    }
    __syncthreads();

    if (i < ntile && h == 0) {
        const float* p = &tile[i * DDIM];
        float a = p[0], b1 = p[1];
        float m = fmaxf(a, b1);
        float ea = expf(a - m), eb = expf(b1 - m);
        float score = eb / (ea + eb);
        float g0 = p[2], g1 = p[3], g2 = p[4], g3 = p[5];
#pragma unroll
        for (int l = 0; l < LDIM; ++l) {
            float geo = fabsf(g0 - tg_geo[l][0]) + fabsf(g1 - tg_geo[l][1])
                      + fabsf(g2 - tg_geo[l][2]) + fabsf(g3 - tg_geo[l][3]);
            float off_t = (offs[l] + part[i][l]) / 72.0f;
            costws[((size_t)(branch * NSB + sb) * LDIM + l) * NPRI + n]
                = geo + off_t - score;
        }
    }
}

// ---------------------------------------------------------------------------
// Kernel 2: greedy assignment from precomputed cost. grid (96, 2), block 256.
// jnp.argmin semantics: first occurrence wins ties; used rows masked to +inf.
__global__ __launch_bounds__(256) void greedy_kernel(
    const float* __restrict__ costws, int* __restrict__ rowsws)
{
    const int sb = blockIdx.x, branch = blockIdx.y;
    const int tid = threadIdx.x;

    __shared__ float cost[LDIM][NPRI];   // 32,000 B
    __shared__ float red_val[256];
    __shared__ int   red_idx[256];

    const float4* src = (const float4*)(costws + (size_t)(branch * NSB + sb) * LDIM * NPRI);
    float4* dst = (float4*)&cost[0][0];
    for (int k = tid; k < LDIM * NPRI / 4; k += 256) dst[k] = src[k];
    __syncthreads();

    for (int l = 0; l < LDIM; ++l) {
        float bv = INFINITY; int bi = 0x7fffffff;
        for (int n = tid; n < NPRI; n += 256) {
            float v = cost[l][n];
            if (v < bv) { bv = v; bi = n; }   // strict < keeps first occurrence
        }
        red_val[tid] = bv; red_idx[tid] = bi;
        __syncthreads();
        for (int s = 128; s > 0; s >>= 1) {
            if (tid < s) {
                float v2 = red_val[tid + s]; int i2 = red_idx[tid + s];
                if (v2 < red_val[tid] || (v2 == red_val[tid] && i2 < red_idx[tid])) {
                    red_val[tid] = v2; red_idx[tid] = i2;
                }
            }
            __syncthreads();
        }
        int r = red_idx[0];
        if (tid == 0) {
            rowsws[(branch * NSB + sb) * LDIM + l] = r;
            cost[0][r] = INFINITY; cost[1][r] = INFINITY;
            cost[2][r] = INFINITY; cost[3][r] = INFINITY;
        }
        __syncthreads();
    }
}

// ---------------------------------------------------------------------------
// Kernel 3: reduce negcls over sb -> clsSum[branch][n] (raw sum, scaled later)
// grid (8, 2), block 256; coalesced over n, 4 accumulators for MLP.
__global__ __launch_bounds__(256) void clsreduce_kernel(
    const float* __restrict__ negws, float* __restrict__ clsSum)
{
    const int branch = blockIdx.y;
    const int n = blockIdx.x * 256 + threadIdx.x;
    if (n >= NPRI) return;
    const float* src = negws + (size_t)branch * NSB * NPRI + n;
    float a0 = 0.f, a1 = 0.f, a2 = 0.f, a3 = 0.f;
    for (int sb = 0; sb < NSB; sb += 4) {
        a0 += src[(size_t)(sb + 0) * NPRI];
        a1 += src[(size_t)(sb + 1) * NPRI];
        a2 += src[(size_t)(sb + 2) * NPRI];
        a3 += src[(size_t)(sb + 3) * NPRI];
    }
    clsSum[branch * NPRI + n] = (a0 + a1) + (a2 + a3);
}

// ---------------------------------------------------------------------------
// Kernel 4: reg (smooth-L1) + line-IoU on matched priors, reduced to [L].
// grid: 2 blocks (one per branch), block 384. out[0..3]=reg, out[4..7]=iou
__global__ __launch_bounds__(384) void regiou_kernel(
    const float* __restrict__ predsA, const float* __restrict__ predsB,
    const float* __restrict__ gt, const int* __restrict__ rowsws,
    float* __restrict__ regiou)
{
    const int branch = blockIdx.x;
    const float* preds = branch ? predsB : predsA;
    const int* rows = rowsws + branch * NSB * LDIM;
    float* out = regiou + branch * 8;

    __shared__ float regbuf[NSB * LDIM];
    __shared__ float ioubuf[NSB * LDIM];

    const int t = threadIdx.x;
    const int l = t & 3, sb = t >> 2;
    const int bimg = sb % BDIM;
    const int rr = rows[sb * LDIM + l];
    const float* pm = preds + ((size_t)sb * NPRI + rr) * DDIM;
    const float* tg = gt + ((size_t)bimg * LDIM + l) * DDIM;

    const float scv[4] = {71.0f, 799.0f, 180.0f, 71.0f};
    float rsum = 0.0f;
#pragma unroll
    for (int j = 0; j < 4; ++j) {
        float d = pm[2 + j] * scv[j] - tg[2 + j] * scv[j];
        float ad = fabsf(d);
        rsum += (ad < 1.0f) ? 0.5f * d * d : ad - 0.5f;
    }
    regbuf[t] = (rsum / 4.0f) / 4.0f;

    float osum = 0.0f, usum = 0.0f;
    for (int j = 0; j < NOFF; ++j) {
        float rp = pm[6 + j] * 799.0f;
        float rt = tg[6 + j];
        float ov = fminf(rp + 15.0f, rt + 15.0f) - fmaxf(rp - 15.0f, rt - 15.0f);
        float un = fmaxf(rp + 15.0f, rt + 15.0f) - fminf(rp - 15.0f, rt - 15.0f);
        bool inv = (rt < 0.0f) || (rt >= 800.0f);
        if (inv) { ov = 0.0f; un = 0.0f; }
        osum += ov; usum += un;
    }
    float iou = osum / (usum + 1e-9f);
    ioubuf[t] = (1.0f - iou) / 4.0f;
    __syncthreads();

    if (t < 8) {
        int l2 = t & 3; bool isiou = t >= 4;
        const float* buf = isiou ? ioubuf : regbuf;
        float s = 0.0f;
        for (int sb2 = 0; sb2 < NSB; ++sb2) s += buf[sb2 * LDIM + l2];
        out[t] = s / 96.0f;
    }
}

// ---------------------------------------------------------------------------
// Kernel 5: focal corrections for matched priors, inst vectors, exact median
// (bitonic, 2048 padded +inf), weighted sum -> scalar. 1 block, 1024 threads.
__global__ __launch_bounds__(1024) void final_kernel(
    const float* __restrict__ predsA, const float* __restrict__ predsB,
    const float* __restrict__ clsSum, const float* __restrict__ regiou,
    const int* __restrict__ rowsws, const float* __restrict__ diff,
    float* __restrict__ out)
{
    __shared__ float corr[2][NPRI];    // 16,000 B
    __shared__ float instA[NPRI];
    __shared__ float instB[NPRI];
    __shared__ float sbuf[2048];
    __shared__ float red[1024];
    const int tid = threadIdx.x;

    for (int k = tid; k < 2 * NPRI; k += 1024) corr[0][k] = 0.0f;
    __syncthreads();

    // 768 matched (branch, sb, l) entries: pos-focal minus neg-focal correction
    if (tid < 2 * NSB * LDIM) {
        int branch = tid / (NSB * LDIM);
        int idx = tid % (NSB * LDIM);
        int sb = idx >> 2, l = idx & 3;
        int r = rowsws[(branch * NSB + sb) * LDIM + l];
        const float* p = (branch ? predsB : predsA) + ((size_t)sb * NPRI + r) * DDIM;
        float a = p[0], b1 = p[1];
        float m = fmaxf(a, b1);
        float ea = expf(a - m), eb = expf(b1 - m);
        float lse = m + logf(ea + eb);
        float lp0 = a - lse, lp1 = b1 - lse;
        float pt0 = expf(lp0), pt1 = expf(lp1);
        float om0 = 1.0f - pt0, om1 = 1.0f - pt1;
        float neg = -(0.1f * om0 * om0 * lp0);
        float pos = -(0.9f * om1 * om1 * lp1);
        atomicAdd(&corr[branch][r], pos - neg);
    }
    __syncthreads();

    const float cls_scale = 2.0f / 96.0f;   // CLS_W / (B*S)
    for (int n = tid; n < NPRI; n += 1024) {
        float ia = (clsSum[n] + corr[0][n]) * cls_scale;
        float ib = (clsSum[NPRI + n] + corr[1][n]) * cls_scale;
#pragma unroll
        for (int l = 0; l < 4; ++l) {
            if (rowsws[(NSB - 1) * LDIM + l] == n)
                ia += regiou[l] * 0.5f + regiou[4 + l] * 2.0f;
            if (rowsws[(NSB + NSB - 1) * LDIM + l] == n)
                ib += regiou[8 + l] * 0.5f + regiou[12 + l] * 2.0f;
        }
        instA[n] = ia; instB[n] = ib;
        sbuf[n] = ia - ib;
    }
    if (tid < 2048 - NPRI) sbuf[NPRI + tid] = INFINITY;
    __syncthreads();

    for (int k = 2; k <= 2048; k <<= 1) {
        for (int j = k >> 1; j > 0; j >>= 1) {
            for (int i = tid; i < 2048; i += 1024) {
                int ixj = i ^ j;
                if (ixj > i) {
                    bool up = ((i & k) == 0);
                    float x = sbuf[i], y = sbuf[ixj];
                    if ((x > y) == up) { sbuf[i] = y; sbuf[ixj] = x; }
                }
            }
            __syncthreads();
        }
    }
    float delta = 0.5f * (sbuf[999] + sbuf[1000]);

    float acc = 0.0f;
    for (int n = tid; n < NPRI; n += 1024) {
        float dm = (diff[n] + diff[NPRI + n] + diff[2 * NPRI + n]) / 3.0f;
        acc += (1.0f - dm) * (instA[n] - 0.5f * delta)
             + dm * (instB[n] + 0.5f * delta);
    }
    red[tid] = acc;
    __syncthreads();
    for (int s = 512; s > 0; s >>= 1) {
        if (tid < s) red[tid] += red[tid + s];
        __syncthreads();
    }
    if (tid == 0) out[0] = red[0];
}

// ---------------------------------------------------------------------------
extern "C" void kernel_launch(void* const* d_in, const int* in_sizes, int n_in,
                              void* d_out, int out_size, void* d_ws, size_t ws_size,
                              hipStream_t stream)
{
    const float* predsA = (const float*)d_in[0];   // [3,32,2000,78]
    const float* predsB = (const float*)d_in[1];   // [3,32,2000,78]
    const float* gt     = (const float*)d_in[2];   // [32,4,78]
    const float* diff   = (const float*)d_in[3];   // [3,2000]
    float* out = (float*)d_out;

    float* costws = (float*)d_ws;                         // 1,536,000 f
    float* negws  = costws + 2 * NSB * LDIM * NPRI;       //   384,000 f
    int*   rowsws = (int*)(negws + 2 * NSB * NPRI);       //       768 i
    float* clsSum = (float*)(rowsws + 2 * NSB * LDIM);    //     4,000 f
    float* regiou = clsSum + 2 * NPRI;                    //        16 f

    dim3 g1(NCHUNK, NSB, 2);
    cost_kernel<<<g1, 256, 0, stream>>>(predsA, predsB, gt, costws, negws);

    dim3 g2(NSB, 2);
    greedy_kernel<<<g2, 256, 0, stream>>>(costws, rowsws);

    dim3 g3((NPRI + 255) / 256, 2);
    clsreduce_kernel<<<g3, 256, 0, stream>>>(negws, clsSum);

    regiou_kernel<<<2, 384, 0, stream>>>(predsA, predsB, gt, rowsws, regiou);

    final_kernel<<<1, 1024, 0, stream>>>(predsA, predsB, clsSum, regiou,
                                         rowsws, diff, out);
}